// Round 12
// baseline (261.305 us; speedup 1.0000x reference)
//
#include <hip/hip_runtime.h>

// Problem constants (fixed by setup_inputs)
#define NT    8           // timesteps
#define NB    16          // batch
#define FS    262144      // C*H*W (= 2^18)
#define DTPB  512         // data threads (8 waves) — layout identical to R9
#define TPB   576         // + 1 dedicated protocol wave (wid 8)
#define NW    8           // data waves
#define BPB   16          // blocks per batch
#define GRID  (NB*BPB)    // 256 blocks = 1 per CU (best measured config, R9)
#define CHK   8           // float4 chunks/thread -> 32 elems/thread
#define ELB   (DTPB*CHK*4)// 16384 elems per block
#define SPIN_CAP (1L<<26)

// Fence-free bias-carrying accumulators (all atomics RELAXED):
//   16 arrivals/line: value >= 16*BIAS <=> all in. No early trigger:
//   15*2^26 + max Sum(bs) (~3e6) << 2^30; 15*2^19 + 2^18 < 2^23.
#define K_BIAS  67108864.0          // 2^26
#define TGT_D   1073741824.0        // 16*K = 2^30, exactly representable
#define B_BIAS  524288              // 2^19
#define TGT_I   8388608             // 16*B = 2^23

// ws layout (zeroed every launch), all slots padded to own 64B line:
//   acc double @ (t*NB+b)*64           8 KB   |m|-sum accumulators
//   cnt int    @ 8192 + (t*NB+b)*64    8 KB   spike-count accumulators
#define WS_NEED 16384

__device__ __forceinline__ void bar_lds() {
    // raw workgroup barrier draining ONLY LDS (lgkmcnt): in-flight global
    // prefetches ride through (unlike __syncthreads' vmcnt(0) drain).
    __builtin_amdgcn_sched_barrier(0);
    asm volatile("s_waitcnt lgkmcnt(0)" ::: "memory");
    __builtin_amdgcn_s_barrier();
    __builtin_amdgcn_sched_barrier(0);
}

// R11 CONFOUND FIX: bare __launch_bounds__(576) let the compiler cap VGPRs
// at 84 -> u[32] spilled to scratch (WRITE_SIZE 17->104 MB, +30 us). The
// explicit min-waves arg (2/EU -> 256-VGPR cap) restores the R9 allocation.
__global__ __launch_bounds__(TPB, 2)
void bispike_kernel(const float* __restrict__ x,
                    const float* __restrict__ decay_p,
                    const float* __restrict__ vth_p,
                    const float* __restrict__ W1,
                    const float* __restrict__ b1,
                    const float* __restrict__ W2,
                    const float* __restrict__ b2,
                    const float* __restrict__ att_w,
                    float* __restrict__ out,
                    char* __restrict__ wsb)
{
    const int tid  = threadIdx.x;
    const int lane = tid & 63;
    const int wid  = tid >> 6;          // 0..8
    const bool pw  = (wid == NW);       // dedicated protocol wave: never loads x
    const int b    = blockIdx.x & 15;   // XCD-local batches (R9 mapping)
    const int bg   = blockIdx.x >> 4;   // 0..15

    const double dec  = 1.0 / (1.0 + exp(-(double)decay_p[0]));
    const double vth  = (double)vth_p[0];
    const double csub = dec * vth;      // loop-invariant spike correction

    double   u[CHK * 4];                // unnormalized membrane m_t (fp64)
    float4   xv[CHK];                   // prefetched x (fp32 in memory)
    unsigned sm[NT];                    // spike bits (32 used)
    int      csave = 0;                 // prev-step wave count (lane0 valid)

    double lsum = 0.0;
    if (!pw) {   // t=0: m_0 = x_0 (carry is zero)
        const float* p = x + (size_t)b * FS + (size_t)bg * ELB + tid * 4;
        #pragma unroll
        for (int k = 0; k < CHK; ++k) xv[k] = *(const float4*)(p + k * (DTPB * 4));
        double n0 = 0.0, n1 = 0.0, n2 = 0.0, n3 = 0.0;
        #pragma unroll
        for (int k = 0; k < CHK; ++k) {
            u[k*4+0] = (double)xv[k].x; n0 += fabs(u[k*4+0]);
            u[k*4+1] = (double)xv[k].y; n1 += fabs(u[k*4+1]);
            u[k*4+2] = (double)xv[k].z; n2 += fabs(u[k*4+2]);
            u[k*4+3] = (double)xv[k].w; n3 += fabs(u[k*4+3]);
        }
        lsum = (n0 + n1) + (n2 + n3);
    }

    __shared__ double dred[NW];
    __shared__ double denom_s;
    __shared__ int    ired[NT][NW];

    #pragma unroll 1
    for (int t = 0; t < NT; ++t) {
        if (!pw) {
            // ALL data waves prefetch early — rides through raw barriers;
            // the protocol wave's vmcnt FIFO stays permanently clean.
            if (t < NT - 1) {
                const float* p = x + ((size_t)(t + 1) * NB + b) * FS
                                   + (size_t)bg * ELB + tid * 4;
                #pragma unroll
                for (int k = 0; k < CHK; ++k)
                    xv[k] = *(const float4*)(p + k * (DTPB * 4));
            }
            // wave partial of sum |m_t|
            double ls = lsum;
            #pragma unroll
            for (int off = 32; off > 0; off >>= 1)
                ls += __shfl_down(ls, off, 64);
            if (lane == 0) {
                dred[wid] = ls;
                if (t > 0) ired[t - 1][wid] = csave;   // counts ride along
            }
        }
        bar_lds();

        if (pw && lane == 0) {
            // protocol wave: clean FIFO -> RMW return & polls never queue
            // behind prefetches (vmcnt is FIFO-ordered per wave).
            double bs = 0.0;
            #pragma unroll
            for (int w = 0; w < NW; ++w) bs += dred[w];
            double* acc = (double*)(wsb + (size_t)(t * NB + b) * 64);
            double ret = __hip_atomic_fetch_add(acc, bs + K_BIAS,
                             __ATOMIC_RELAXED, __HIP_MEMORY_SCOPE_AGENT);
            double v = ret + (bs + K_BIAS);
            if (v < TGT_D - 1.0) {
                long it = 0;
                for (;;) {
                    v = __hip_atomic_load(acc, __ATOMIC_RELAXED,
                                          __HIP_MEMORY_SCOPE_AGENT);
                    if (v >= TGT_D - 1.0) break;
                    if (++it > SPIN_CAP) break;
                    __builtin_amdgcn_s_sleep(2);
                }
            }
            denom_s = (v - TGT_D) / (double)FS + 1e-6;  // exact /2^18
        }
        bar_lds();
        const double denom = denom_s;

        if (!pw) {
            // fused threshold + advance:
            //   s_t = (u >= vth*D_t);  u' = (dec/D_t)*u + x' - s_t*(dec*vth)
            const double thr = vth * denom;
            const double a   = dec * (1.0 / denom);
            unsigned smt = 0;
            if (t < NT - 1) {
                double n0 = 0.0, n1 = 0.0, n2 = 0.0, n3 = 0.0;
                #pragma unroll
                for (int k = 0; k < CHK; ++k) {
                    const double xn0 = (double)xv[k].x, xn1 = (double)xv[k].y,
                                 xn2 = (double)xv[k].z, xn3 = (double)xv[k].w;
                    double un;
                    bool s0 = (u[k*4+0] >= thr); if (s0) smt |= 1u << (k*4+0);
                    un = fma(a, u[k*4+0], xn0); if (s0) un -= csub;
                    u[k*4+0] = un; n0 += fabs(un);
                    bool s1 = (u[k*4+1] >= thr); if (s1) smt |= 1u << (k*4+1);
                    un = fma(a, u[k*4+1], xn1); if (s1) un -= csub;
                    u[k*4+1] = un; n1 += fabs(un);
                    bool s2 = (u[k*4+2] >= thr); if (s2) smt |= 1u << (k*4+2);
                    un = fma(a, u[k*4+2], xn2); if (s2) un -= csub;
                    u[k*4+2] = un; n2 += fabs(un);
                    bool s3 = (u[k*4+3] >= thr); if (s3) smt |= 1u << (k*4+3);
                    un = fma(a, u[k*4+3], xn3); if (s3) un -= csub;
                    u[k*4+3] = un; n3 += fabs(un);
                }
                lsum = (n0 + n1) + (n2 + n3);
            } else {
                #pragma unroll
                for (int j = 0; j < CHK * 4; ++j)
                    if (u[j] >= thr) smt |= 1u << j;
            }
            sm[t] = smt;
            // wave-reduce this step's spike count now (published next round)
            int c = __popc(smt);
            #pragma unroll
            for (int off = 32; off > 0; off >>= 1)
                c += __shfl_down(c, off, 64);
            csave = c;
        } else if (lane == 0 && t > 0) {
            // protocol wave, in the shadow of data-wave compute:
            // publish cnt[t-1]; drains from FIFO before the next poll.
            int tot = 0;
            #pragma unroll
            for (int w = 0; w < NW; ++w) tot += ired[t - 1][w];
            (void)__hip_atomic_fetch_add(
                (int*)(wsb + 8192 + (size_t)((t - 1) * NB + b) * 64),
                tot + B_BIAS, __ATOMIC_RELAXED, __HIP_MEMORY_SCOPE_AGENT);
        }
    }

    // ---- epilogue: publish cnt[7], poll all 8 count lines ----
    if (!pw && lane == 0) ired[NT - 1][wid] = csave;
    __syncthreads();

    __shared__ int totc_s[NT];
    __shared__ double summ_s[NT];

    if (pw) {
        if (lane == 0) {
            int tot = 0;
            #pragma unroll
            for (int w = 0; w < NW; ++w) tot += ired[NT - 1][w];
            (void)__hip_atomic_fetch_add(
                (int*)(wsb + 8192 + (size_t)((NT - 1) * NB + b) * 64),
                tot + B_BIAS, __ATOMIC_RELAXED, __HIP_MEMORY_SCOPE_AGENT);
        }
        int* cp = (int*)(wsb + 8192 + (size_t)(lane * NB + b) * 64);
        int v = TGT_I;                   // lanes >= NT: already "done"
        if (lane < NT)
            v = __hip_atomic_load(cp, __ATOMIC_RELAXED,
                                  __HIP_MEMORY_SCOPE_AGENT);
        long it = 0;
        while (!__all(v >= TGT_I)) {
            if (lane < NT && v < TGT_I)
                v = __hip_atomic_load(cp, __ATOMIC_RELAXED,
                                      __HIP_MEMORY_SCOPE_AGENT);
            if (++it > SPIN_CAP) break;
            __builtin_amdgcn_s_sleep(2);
        }
        if (lane < NT) totc_s[lane] = v - TGT_I;   // exact int total
    }
    __syncthreads();
    if (tid < NT)
        summ_s[tid] = (double)totc_s[tid] / (double)FS;    // exact
    __syncthreads();

    // ---- tiny MLP attention in fp64, redundantly per block ----
    __shared__ double h_s[4 * 64];
    __shared__ double wmat_s[NT];
    if (tid < 256) {
        int nh = tid >> 6, hd = tid & 63;
        double acc = 0.0;
        #pragma unroll
        for (int t = 0; t < NT; ++t)
            acc += summ_s[t] * (double)W1[nh * 512 + hd * 8 + t];
        acc += (double)b1[nh * 64 + hd];
        h_s[tid] = fmax(acc, 0.0);
    }
    __syncthreads();
    if (tid < NT) {
        double w = 0.0;
        for (int nh = 0; nh < 4; ++nh) {
            double macc = 0.0;
            for (int hd = 0; hd < 64; ++hd)
                macc += h_s[nh * 64 + hd] * (double)W2[nh * 512 + tid * 64 + hd];
            macc += (double)b2[nh * 8 + tid];
            w += macc * (double)att_w[nh];
        }
        wmat_s[tid] = w;
    }
    __syncthreads();

    // softmax over t in fp64 (per-thread copy)
    double awr[NT];
    {
        double mx = wmat_s[0];
        #pragma unroll
        for (int t = 1; t < NT; ++t) mx = fmax(mx, wmat_s[t]);
        double ss = 0.0;
        #pragma unroll
        for (int t = 0; t < NT; ++t) { awr[t] = exp(wmat_s[t] - mx); ss += awr[t]; }
        #pragma unroll
        for (int t = 0; t < NT; ++t) awr[t] = awr[t] / ss;
    }

    // ---- out[b,f] = sum_t spike_bit * aw[t,b] (fp64 acc, fp32 store) ----
    if (!pw) {
        float* po = out + (size_t)b * FS + (size_t)bg * ELB + tid * 4;
        #pragma unroll
        for (int k = 0; k < CHK; ++k) {
            double o[4] = {0.0, 0.0, 0.0, 0.0};
            #pragma unroll
            for (int t = 0; t < NT; ++t) {
                const unsigned smt = sm[t];
                o[0] += ((smt >> (k * 4 + 0)) & 1) ? awr[t] : 0.0;
                o[1] += ((smt >> (k * 4 + 1)) & 1) ? awr[t] : 0.0;
                o[2] += ((smt >> (k * 4 + 2)) & 1) ? awr[t] : 0.0;
                o[3] += ((smt >> (k * 4 + 3)) & 1) ? awr[t] : 0.0;
            }
            *(float4*)(po + k * (DTPB * 4)) =
                make_float4((float)o[0], (float)o[1], (float)o[2], (float)o[3]);
        }
    }
}

__global__ void diag_kernel(float* out, int code) {
    out[0] = 100000.0f + (float)code;
}

extern "C" void kernel_launch(void* const* d_in, const int* in_sizes, int n_in,
                              void* d_out, int out_size, void* d_ws, size_t ws_size,
                              hipStream_t stream) {
    const float* x     = (const float*)d_in[0];
    const float* decay = (const float*)d_in[1];
    const float* vth   = (const float*)d_in[2];
    const float* W1    = (const float*)d_in[3];
    const float* b1    = (const float*)d_in[4];
    const float* W2    = (const float*)d_in[5];
    const float* b2    = (const float*)d_in[6];
    const float* att   = (const float*)d_in[7];
    float* out = (float*)d_out;

    if (ws_size < WS_NEED) {
        diag_kernel<<<1, 1, 0, stream>>>(out, 999);
        return;
    }

    hipMemsetAsync(d_ws, 0, WS_NEED, stream);

    hipGetLastError();  // clear stale error
    bispike_kernel<<<dim3(GRID), dim3(TPB), 0, stream>>>(
        x, decay, vth, W1, b1, W2, b2, att, out, (char*)d_ws);
    hipError_t err = hipGetLastError();
    if (err != hipSuccess) {
        diag_kernel<<<1, 1, 0, stream>>>(out, (int)err);
    }
}

// Round 13
// 227.686 us; speedup vs baseline: 1.1477x; 1.1477x over previous
//
#include <hip/hip_runtime.h>

// Problem constants (fixed by setup_inputs)
#define NT    8           // timesteps
#define NB    16          // batch
#define FS    262144      // C*H*W (= 2^18)
#define TPB   512         // threads per block (8 waves)
#define NW    8           // waves per block
#define BPB   16          // blocks per batch
#define GRID  (NB*BPB)    // 256 blocks = EXACTLY 1 per CU (best measured: R9)
#define CHK   8           // float4 chunks/thread -> 32 elems/thread
#define ELB   (TPB*CHK*4) // 16384 elems per block
#define SPIN_CAP (1L<<26)

// Fence-free bias-carrying accumulators (all atomics RELAXED):
//   each block adds (payload + BIAS); BIAS doubles as arrival counter.
//   16 arrivals: value >= 16*BIAS. No early trigger: 15*K + max Sum(bs)
//   (~1e6) << 2^30; 15*B + max Sum(cnt) (2^18) < 2^23.
#define K_BIAS  67108864.0          // 2^26
#define TGT_D   1073741824.0        // 16*K = 2^30, exactly representable
#define B_BIAS  524288              // 2^19
#define TGT_I   8388608             // 16*B = 2^23

// ws layout (zeroed every launch), all slots padded to own 64B line:
//   acc double @ (t*NB+b)*64           8 KB   |m|-sum accumulators
//   cnt int    @ 8192 + (t*NB+b)*64    8 KB   spike-count accumulators
#define WS_NEED 16384

__device__ __forceinline__ void bar_lds() {
    // raw workgroup barrier draining ONLY LDS (lgkmcnt): in-flight global
    // prefetches ride through (unlike __syncthreads' vmcnt(0) drain).
    __builtin_amdgcn_sched_barrier(0);
    asm volatile("s_waitcnt lgkmcnt(0)" ::: "memory");
    __builtin_amdgcn_s_barrier();
    __builtin_amdgcn_sched_barrier(0);
}

__global__ __launch_bounds__(TPB, 2)
void bispike_kernel(const float* __restrict__ x,
                    const float* __restrict__ decay_p,
                    const float* __restrict__ vth_p,
                    const float* __restrict__ W1,
                    const float* __restrict__ b1,
                    const float* __restrict__ W2,
                    const float* __restrict__ b2,
                    const float* __restrict__ att_w,
                    float* __restrict__ out,
                    char* __restrict__ wsb)
{
    const int tid  = threadIdx.x;
    const int lane = tid & 63;
    const int wid  = tid >> 6;
    const int b    = blockIdx.x & 15;   // XCD-localized: batch b on XCD b%8
    const int bg   = blockIdx.x >> 4;   // 0..15

    const double dec  = 1.0 / (1.0 + exp(-(double)decay_p[0]));
    const double vth  = (double)vth_p[0];
    const double csub = dec * vth;      // loop-invariant spike correction

    double   u[CHK * 4];                // unnormalized membrane m_t (fp64)
    float4   xv[CHK];                   // prefetched x (fp32 in memory)
    unsigned sm[NT];                    // spike bits (32 used)

    {   // t=0: m_0 = x_0 (carry is zero)
        const float* p = x + (size_t)b * FS + (size_t)bg * ELB + tid * 4;
        #pragma unroll
        for (int k = 0; k < CHK; ++k) xv[k] = *(const float4*)(p + k * (TPB * 4));
    }
    double lsum;
    {
        double n0 = 0.0, n1 = 0.0, n2 = 0.0, n3 = 0.0;
        #pragma unroll
        for (int k = 0; k < CHK; ++k) {
            u[k*4+0] = (double)xv[k].x; n0 += fabs(u[k*4+0]);
            u[k*4+1] = (double)xv[k].y; n1 += fabs(u[k*4+1]);
            u[k*4+2] = (double)xv[k].z; n2 += fabs(u[k*4+2]);
            u[k*4+3] = (double)xv[k].w; n3 += fabs(u[k*4+3]);
        }
        lsum = (n0 + n1) + (n2 + n3);
    }

    __shared__ double dred[NW];
    __shared__ double denom_s;

    #pragma unroll 1
    for (int t = 0; t < NT; ++t) {
        // ALL waves prefetch early (rides through raw barriers; wave0's RMW
        // result shares vmcnt with these — they complete concurrently)
        if (t < NT - 1) {
            const float* p = x + ((size_t)(t + 1) * NB + b) * FS
                               + (size_t)bg * ELB + tid * 4;
            #pragma unroll
            for (int k = 0; k < CHK; ++k) xv[k] = *(const float4*)(p + k * (TPB * 4));
        }

        // ---- wave partial of sum |m_t| ----
        double ls = lsum;
        #pragma unroll
        for (int off = 32; off > 0; off >>= 1)
            ls += __shfl_down(ls, off, 64);
        if (lane == 0) dred[wid] = ls;
        bar_lds();

        if (wid == 0) {
            if (lane == 0) {
                const double bs = (((dred[0] + dred[1]) + (dred[2] + dred[3]))
                                 + ((dred[4] + dred[5]) + (dred[6] + dred[7])));
                // single relaxed RMW: payload + bias; bias counts arrivals
                double* acc = (double*)(wsb + (size_t)(t * NB + b) * 64);
                double ret = __hip_atomic_fetch_add(acc, bs + K_BIAS,
                                 __ATOMIC_RELAXED, __HIP_MEMORY_SCOPE_AGENT);
                double v = ret + (bs + K_BIAS);
                if (v < TGT_D - 1.0) {          // not last: poll (payload=flag)
                    long it = 0;
                    for (;;) {
                        v = __hip_atomic_load(acc, __ATOMIC_RELAXED,
                                              __HIP_MEMORY_SCOPE_AGENT);
                        if (v >= TGT_D - 1.0) break;
                        if (++it > SPIN_CAP) break;
                        __builtin_amdgcn_s_sleep(2);
                    }
                }
                // mean exact /2^18; order+bias perturbation ~1e-12 relative
                denom_s = (v - TGT_D) / (double)FS + 1e-6;
            }
        }
        bar_lds();
        const double denom = denom_s;

        // fused threshold + advance:
        //   s_t = (u >= vth*D_t);  u' = (dec/D_t)*u + x' - s_t*(dec*vth)
        const double thr = vth * denom;
        const double a   = dec * (1.0 / denom);
        unsigned smt = 0;
        if (t < NT - 1) {
            double n0 = 0.0, n1 = 0.0, n2 = 0.0, n3 = 0.0;
            #pragma unroll
            for (int k = 0; k < CHK; ++k) {
                const double xn0 = (double)xv[k].x, xn1 = (double)xv[k].y,
                             xn2 = (double)xv[k].z, xn3 = (double)xv[k].w;
                double un;
                bool s0 = (u[k*4+0] >= thr); if (s0) smt |= 1u << (k*4+0);
                un = fma(a, u[k*4+0], xn0); if (s0) un -= csub;
                u[k*4+0] = un; n0 += fabs(un);
                bool s1 = (u[k*4+1] >= thr); if (s1) smt |= 1u << (k*4+1);
                un = fma(a, u[k*4+1], xn1); if (s1) un -= csub;
                u[k*4+1] = un; n1 += fabs(un);
                bool s2 = (u[k*4+2] >= thr); if (s2) smt |= 1u << (k*4+2);
                un = fma(a, u[k*4+2], xn2); if (s2) un -= csub;
                u[k*4+2] = un; n2 += fabs(un);
                bool s3 = (u[k*4+3] >= thr); if (s3) smt |= 1u << (k*4+3);
                un = fma(a, u[k*4+3], xn3); if (s3) un -= csub;
                u[k*4+3] = un; n3 += fabs(un);
            }
            lsum = (n0 + n1) + (n2 + n3);
        } else {
            #pragma unroll
            for (int j = 0; j < CHK * 4; ++j)
                if (u[j] >= thr) smt |= 1u << j;
        }
        sm[t] = smt;
    }

    // ---- spike counts per (t,b): exact ints, same fence-free protocol ----
    __shared__ int ired[NT][NW];
    #pragma unroll
    for (int t = 0; t < NT; ++t) {
        int c = __popc(sm[t]);
        #pragma unroll
        for (int off = 32; off > 0; off >>= 1)
            c += __shfl_down(c, off, 64);
        if (lane == 0) ired[t][wid] = c;
    }
    __syncthreads();

    __shared__ int totc_s[NT];
    __shared__ double summ_s[NT];

    if (wid == 0) {
        int* cp = (int*)(wsb + 8192 + (size_t)(lane * NB + b) * 64);
        int v = TGT_I;                   // lanes >= NT: already "done"
        if (lane < NT) {
            int tot = 0;
            #pragma unroll
            for (int w = 0; w < NW; ++w) tot += ired[lane][w];
            int ret = __hip_atomic_fetch_add(cp, tot + B_BIAS,
                          __ATOMIC_RELAXED, __HIP_MEMORY_SCOPE_AGENT);
            v = ret + tot + B_BIAS;
        }
        long it = 0;
        while (!__all(v >= TGT_I)) {
            if (lane < NT && v < TGT_I)
                v = __hip_atomic_load(cp, __ATOMIC_RELAXED,
                                      __HIP_MEMORY_SCOPE_AGENT);
            if (++it > SPIN_CAP) break;
            __builtin_amdgcn_s_sleep(2);
        }
        if (lane < NT) totc_s[lane] = v - TGT_I;   // exact int total
    }
    __syncthreads();
    if (tid < NT)
        summ_s[tid] = (double)totc_s[tid] / (double)FS;    // exact
    __syncthreads();

    // ---- tiny MLP attention in fp64, redundantly per block ----
    __shared__ double h_s[4 * 64];
    __shared__ double wmat_s[NT];
    if (tid < 256) {
        int nh = tid >> 6, hd = tid & 63;
        double acc = 0.0;
        #pragma unroll
        for (int t = 0; t < NT; ++t)
            acc += summ_s[t] * (double)W1[nh * 512 + hd * 8 + t];
        acc += (double)b1[nh * 64 + hd];
        h_s[tid] = fmax(acc, 0.0);
    }
    __syncthreads();
    if (tid < NT) {
        double w = 0.0;
        for (int nh = 0; nh < 4; ++nh) {
            double macc = 0.0;
            for (int hd = 0; hd < 64; ++hd)
                macc += h_s[nh * 64 + hd] * (double)W2[nh * 512 + tid * 64 + hd];
            macc += (double)b2[nh * 8 + tid];
            w += macc * (double)att_w[nh];
        }
        wmat_s[tid] = w;
    }
    __syncthreads();

    // softmax over t in fp64 (per-thread copy)
    double awr[NT];
    {
        double mx = wmat_s[0];
        #pragma unroll
        for (int t = 1; t < NT; ++t) mx = fmax(mx, wmat_s[t]);
        double ss = 0.0;
        #pragma unroll
        for (int t = 0; t < NT; ++t) { awr[t] = exp(wmat_s[t] - mx); ss += awr[t]; }
        #pragma unroll
        for (int t = 0; t < NT; ++t) awr[t] = awr[t] / ss;
    }

    // ---- out[b,f] = sum_t spike_bit * aw[t,b] (fp64 acc, fp32 store) ----
    float* po = out + (size_t)b * FS + (size_t)bg * ELB + tid * 4;
    #pragma unroll
    for (int k = 0; k < CHK; ++k) {
        double o[4] = {0.0, 0.0, 0.0, 0.0};
        #pragma unroll
        for (int t = 0; t < NT; ++t) {
            const unsigned smt = sm[t];
            o[0] += ((smt >> (k * 4 + 0)) & 1) ? awr[t] : 0.0;
            o[1] += ((smt >> (k * 4 + 1)) & 1) ? awr[t] : 0.0;
            o[2] += ((smt >> (k * 4 + 2)) & 1) ? awr[t] : 0.0;
            o[3] += ((smt >> (k * 4 + 3)) & 1) ? awr[t] : 0.0;
        }
        *(float4*)(po + k * (TPB * 4)) =
            make_float4((float)o[0], (float)o[1], (float)o[2], (float)o[3]);
    }
}

__global__ void diag_kernel(float* out, int code) {
    out[0] = 100000.0f + (float)code;
}

extern "C" void kernel_launch(void* const* d_in, const int* in_sizes, int n_in,
                              void* d_out, int out_size, void* d_ws, size_t ws_size,
                              hipStream_t stream) {
    const float* x     = (const float*)d_in[0];
    const float* decay = (const float*)d_in[1];
    const float* vth   = (const float*)d_in[2];
    const float* W1    = (const float*)d_in[3];
    const float* b1    = (const float*)d_in[4];
    const float* W2    = (const float*)d_in[5];
    const float* b2    = (const float*)d_in[6];
    const float* att   = (const float*)d_in[7];
    float* out = (float*)d_out;

    if (ws_size < WS_NEED) {
        diag_kernel<<<1, 1, 0, stream>>>(out, 999);
        return;
    }

    hipMemsetAsync(d_ws, 0, WS_NEED, stream);

    hipGetLastError();  // clear stale error
    bispike_kernel<<<dim3(GRID), dim3(TPB), 0, stream>>>(
        x, decay, vth, W1, b1, W2, b2, att, out, (char*)d_ws);
    hipError_t err = hipGetLastError();
    if (err != hipSuccess) {
        diag_kernel<<<1, 1, 0, stream>>>(out, (int)err);
    }
}